// Round 21
// baseline (394.485 us; speedup 1.0000x reference)
//
#include <hip/hip_runtime.h>
#include <math.h>
#include <stdint.h>

#define Bc 16
#define Cc 96
#define Hh 128
#define Ww 128
#define NPIX 16384
#define Mm 12
#define CR 6
#define PAD 3

// conv tile geometry: f16 LDS tile, stride 80 f16 (160B rows).
#define CTH 32
#define CTW 64
#define TROWS 38
#define TCOLS2 72          // staged cols
#define TSH 80             // f16 stride

// fallback k_sample channel split
#define CGROUPS 6
#define CPG 16

typedef float f2 __attribute__((ext_vector_type(2), aligned(4)));
typedef _Float16 h8 __attribute__((ext_vector_type(8)));   // 16B f16 vector
typedef _Float16 h2 __attribute__((ext_vector_type(2)));   // packed f16 pair

union HU { uint32_t u; h2 h; };
union H8U { h8 v; uint32_t u[4]; };

// -------------------- K1: depthwise 7x7 conv + bias (packed-f16 inner loop)
__global__ __launch_bounds__(256) void k_conv(const float* __restrict__ x,
        const float* __restrict__ dw_w, const float* __restrict__ dw_b,
        _Float16* __restrict__ f, float* __restrict__ partial) {
    const int bc = blockIdx.z;
    const int c = bc % Cc;
    __shared__ _Float16 tile[TROWS * TSH];
    __shared__ uint32_t wp2[49];           // f16 splat-pairs {w,w}
    __shared__ float red[256];
    const int tid = threadIdx.x;
    if (tid < 49) {
        _Float16 wh = (_Float16)dw_w[c * 49 + tid];
        HU u; u.h = (h2){wh, wh};
        wp2[tid] = u.u;
    }
    const int ox0 = blockIdx.x * CTW, oy0 = blockIdx.y * CTH;
    const float* xp = x + (size_t)bc * NPIX;
    for (int i = tid; i < TROWS * TCOLS2; i += 256) {
        int r = i / TCOLS2, cc2 = i % TCOLS2;
        int gy = oy0 + r - PAD, gx = ox0 + cc2 - PAD;
        float v = 0.f;
        if (gy >= 0 && gy < Hh && gx >= 0 && gx < Ww) v = xp[gy * Ww + gx];
        tile[r * TSH + cc2] = (_Float16)v;
    }
    __syncthreads();
    const int tx = tid & 7;
    const int ty = tid >> 3;
    const _Float16 biash = (_Float16)dw_b[c];
    h2 acc2[4];
    #pragma unroll
    for (int p = 0; p < 4; ++p) acc2[p] = (h2){biash, biash};
    #pragma unroll
    for (int ky = 0; ky < 7; ++ky) {
        const _Float16* rowp = &tile[(ty + ky) * TSH + tx * 8];
        H8U A, B;
        A.v = *(const h8*)(rowp);
        B.v = *(const h8*)(rowp + 8);
        uint32_t pm[13];
        pm[0]  = A.u[0];
        pm[2]  = A.u[1];
        pm[4]  = A.u[2];
        pm[6]  = A.u[3];
        pm[8]  = B.u[0];
        pm[10] = B.u[1];
        pm[12] = B.u[2];
        pm[1]  = (A.u[0] >> 16) | (A.u[1] << 16);
        pm[3]  = (A.u[1] >> 16) | (A.u[2] << 16);
        pm[5]  = (A.u[2] >> 16) | (A.u[3] << 16);
        pm[7]  = (A.u[3] >> 16) | (B.u[0] << 16);
        pm[9]  = (B.u[0] >> 16) | (B.u[1] << 16);
        pm[11] = (B.u[1] >> 16) | (B.u[2] << 16);
        #pragma unroll
        for (int kx = 0; kx < 7; ++kx) {
            HU w; w.u = wp2[ky * 7 + kx];
            #pragma unroll
            for (int p = 0; p < 4; ++p) {
                HU m; m.u = pm[kx + 2 * p];
                acc2[p] = m.h * w.h + acc2[p];    // v_pk_fma_f16
            }
        }
    }
    _Float16* op = f + (size_t)bc * NPIX + (oy0 + ty) * Ww + ox0 + tx * 8;
    h8 o;
    #pragma unroll
    for (int p = 0; p < 4; ++p) {
        o[2 * p] = acc2[p].x;
        o[2 * p + 1] = acc2[p].y;
    }
    *(h8*)op = o;
    float s = 0.f;
    #pragma unroll
    for (int p = 0; p < 4; ++p)
        s += (float)acc2[p].x + (float)acc2[p].y;
    red[tid] = s;
    __syncthreads();
    for (int st = 128; st > 0; st >>= 1) {
        if (tid < st) red[tid] += red[tid + st];
        __syncthreads();
    }
    if (tid == 0) partial[bc * 8 + blockIdx.y * 2 + blockIdx.x] = red[0];
}

// fast erf (A&S 7.1.26, |err|<=1.5e-7)
__device__ __forceinline__ float fast_gelu(float v) {
    float z = fabsf(v) * 0.70710678118654752440f;
    float t = 1.0f / fmaf(0.3275911f, z, 1.0f);
    float poly = t * fmaf(t, fmaf(t, fmaf(t, fmaf(t, 1.061405429f, -1.453152027f),
                          1.421413741f), -0.284496736f), 0.254829592f);
    float e = exp2f(-1.44269504088896340736f * z * z);
    float erfz = 1.0f - poly * e;
    erfz = (v < 0.0f) ? -erfz : erfz;
    return 0.5f * v * (1.0f + erfz);
}

// -------------------- K3: fused SE-attn + GELU + LN + offset proj
// Round-20 post-mortem: f16-packing u[] ballooned VGPR to 192 (union
// insert/extract). Fix: store NOTHING — two-pass recompute. Pass 1: s1,s2
// (var = E[g^2]-mu^2, validated r20). Pass 2 re-reads f via volatile ptr
// (blocks CSE -> compiler cannot cache the 96 values) and recomputes GELU.
__global__ __launch_bounds__(256) void k_ln_off(const _Float16* __restrict__ f,
        const float* __restrict__ partial, const float* __restrict__ ca_w1,
        const float* __restrict__ ca_w2, const float* __restrict__ ln_g,
        const float* __restrict__ ln_b, const float* __restrict__ off_w,
        float* __restrict__ offs) {
    __shared__ float pm[Cc], hh[CR];
    __shared__ float sa[Cc], sg[Cc], sb[Cc], sw0[Cc], sw1[Cc];
    const int tid = threadIdx.x;
    const int b = blockIdx.x >> 6;
    const int pix = ((blockIdx.x & 63) << 8) + tid;
    if (tid < Cc) {
        float s = 0.f;
        const float* p = partial + (b * Cc + tid) * 8;
        #pragma unroll
        for (int i = 0; i < 8; ++i) s += p[i];
        pm[tid] = s * (1.0f / (float)NPIX);
        sg[tid] = ln_g[tid];
        sb[tid] = ln_b[tid];
        sw0[tid] = off_w[tid];
        sw1[tid] = off_w[Cc + tid];
    }
    __syncthreads();
    if (tid < CR) {
        float s = 0.f;
        for (int c0 = 0; c0 < Cc; ++c0) s = fmaf(ca_w1[tid * Cc + c0], pm[c0], s);
        hh[tid] = fmaxf(s, 0.f);
    }
    __syncthreads();
    if (tid < Cc) {
        float s = 0.f;
        #pragma unroll
        for (int r = 0; r < CR; ++r) s = fmaf(ca_w2[tid * CR + r], hh[r], s);
        sa[tid] = 1.0f / (1.0f + expf(-s));
    }
    __syncthreads();
    const _Float16* fp = f + (size_t)b * Cc * NPIX + pix;
    float s1 = 0.f, s2 = 0.f;
    #pragma unroll
    for (int c = 0; c < Cc; ++c) {
        float g = fast_gelu((float)fp[(size_t)c * NPIX] * sa[c]);
        s1 += g;
        s2 = fmaf(g, g, s2);
    }
    float mu = s1 * (1.0f / (float)Cc);
    float var = fmaxf(s2 * (1.0f / (float)Cc) - mu * mu, 0.f);
    float rs = rsqrtf(var + 1e-5f);
    // pass 2: recompute g (volatile -> no value caching across passes)
    volatile const _Float16* fv = fp;
    float o0 = 0.f, o1 = 0.f;
    #pragma unroll
    for (int c = 0; c < Cc; ++c) {
        float g = fast_gelu((float)fv[(size_t)c * NPIX] * sa[c]);
        float v = (g - mu) * rs * sg[c] + sb[c];
        o0 = fmaf(sw0[c], v, o0);
        o1 = fmaf(sw1[c], v, o1);
    }
    offs[(size_t)b * 2 * NPIX + pix] = o0;
    offs[(size_t)b * 2 * NPIX + NPIX + pix] = o1;
}

// -------------------- K-TRG: fused NCHW->NHWC(f16) transpose + FP64 argmax
__global__ __launch_bounds__(256) void k_trg(const float* __restrict__ x,
        const float* __restrict__ centers, _Float16* __restrict__ xnh,
        int* __restrict__ gid) {
    __shared__ float lds[Cc * 129];
    __shared__ double scn[Mm * Cc];
    __shared__ double pacc[Mm * 129];
    const int bid = blockIdx.x;                // 0..2047
    const int b = bid >> 7;
    const int p0 = (bid & 127) * 128;
    const int t = threadIdx.x;
    const int px = t & 127, crow = t >> 7;
    const float* xp = x + (size_t)b * Cc * NPIX + p0 + px;
    #pragma unroll
    for (int it = 0; it < 48; ++it) {
        const int c = it * 2 + crow;
        lds[c * 129 + px] = xp[(size_t)c * NPIX];
    }
    if (t < Mm) {
        double ss = 0.0;
        #pragma unroll
        for (int c = 0; c < Cc; ++c) {
            double v = (double)centers[t * Cc + c];
            ss += v * v;
        }
        double inv = 1.0 / fmax(sqrt(ss), 1e-12);
        #pragma unroll
        for (int c = 0; c < Cc; ++c)
            scn[t * Cc + c] = (double)centers[t * Cc + c] * inv;
    }
    __syncthreads();
    _Float16* ob = xnh + ((size_t)b * NPIX + p0) * Cc;
    #pragma unroll
    for (int i = 0; i < 6; ++i) {
        const int idx = i * 256 + t;           // 0..1535
        const int gpos = idx * 8;              // f16 index in strip (12288)
        const int ppx = gpos / 96;
        const int c = gpos - ppx * 96;         // multiple of 8
        h8 v;
        #pragma unroll
        for (int k = 0; k < 8; ++k)
            v[k] = (_Float16)lds[(c + k) * 129 + ppx];
        *(h8*)(ob + gpos) = v;
    }
    const int c0 = crow * 48;
    double acc[Mm];
    #pragma unroll
    for (int m = 0; m < Mm; ++m) acc[m] = 0.0;
    for (int cc2 = 0; cc2 < 48; ++cc2) {
        const int c = c0 + cc2;
        double xv = (double)lds[c * 129 + px];
        #pragma unroll
        for (int m = 0; m < Mm; ++m)
            acc[m] = fma(xv, scn[m * Cc + c], acc[m]);
    }
    if (crow == 1) {
        #pragma unroll
        for (int m = 0; m < Mm; ++m) pacc[m * 129 + px] = acc[m];
    }
    __syncthreads();
    if (crow == 0) {
        int bi = 0;
        double bv = acc[0] + pacc[0 * 129 + px];
        #pragma unroll
        for (int m = 1; m < Mm; ++m) {
            double v = acc[m] + pacc[m * 129 + px];
            if (v > bv) { bv = v; bi = m; }
        }
        gid[(size_t)b * NPIX + p0 + px] = bi;
    }
}

// -------------------- K5: stable counting sort; + centers copy (block 0)
__global__ __launch_bounds__(256) void k_sort(const int* __restrict__ gid,
        const float* __restrict__ centers, int* __restrict__ iperm,
        int* __restrict__ permi, float* __restrict__ out) {
    __shared__ int hist[256 * Mm];
    __shared__ int tot[Mm];
    const int t = threadIdx.x;
    const int b = blockIdx.x;
    if (b == 0) {  // centers copy (output 2)
        const size_t base = (size_t)Bc * Cc * NPIX + (size_t)Bc * NPIX;
        for (int i = t; i < Mm * Cc; i += 256) out[base + i] = centers[i];
    }
    for (int i = t; i < 256 * Mm; i += 256) hist[i] = 0;
    __syncthreads();
    const int* gp = gid + (size_t)b * NPIX;
    const int base = t * 64;
    for (int i = 0; i < 64; ++i) hist[t * Mm + gp[base + i]] += 1;
    __syncthreads();
    if (t < Mm) {
        int run = 0;
        for (int r = 0; r < 256; ++r) {
            int v = hist[r * Mm + t];
            hist[r * Mm + t] = run;
            run += v;
        }
        tot[t] = run;
    }
    __syncthreads();
    if (t == 0) {
        int run = 0;
        for (int m = 0; m < Mm; ++m) { int v = tot[m]; tot[m] = run; run += v; }
    }
    __syncthreads();
    int* ip = iperm + (size_t)b * NPIX;
    int* pi = permi + (size_t)b * NPIX;
    float* fperm = out + (size_t)Bc * Cc * NPIX + (size_t)b * NPIX;
    for (int i = 0; i < 64; ++i) {
        int src = base + i;
        int g = gp[src];
        int pos = tot[g] + hist[t * Mm + g];
        hist[t * Mm + g] += 1;
        ip[src] = pos;
        pi[pos] = src;
        fperm[pos] = (float)src;
    }
}

// -------------------- K6-FAST: output-position-ordered f16-NHWC sampler
__global__ __launch_bounds__(256) void k_sample_nhwc(
        const _Float16* __restrict__ xnh, const float* __restrict__ R,
        const float* __restrict__ offs, const int* __restrict__ permi,
        float* __restrict__ out) {
    const int lin = blockIdx.x;                    // 0..4095
    const int swz = (lin & 7) * 512 + (lin >> 3);  // 2 batches per XCD
    const int b = swz >> 8;
    const int jbase = (swz & 255) * 64;
    __shared__ float lds[64 * 97];
    __shared__ float swx[64], swy[64], srb[64];
    __shared__ int sr0[64], sr1[64], shi[64];
    const int t = threadIdx.x;
    if (t < 64) {
        const int src = permi[(size_t)b * NPIX + jbase + t];
        const int hh = src >> 7, wwp = src & 127;
        float o0 = offs[(size_t)b * 2 * NPIX + src];
        float o1 = offs[(size_t)b * 2 * NPIX + NPIX + src];
        float gx = -1.0f + (float)wwp * (2.0f / 127.0f) + o0;
        float gy = -1.0f + (float)hh * (2.0f / 127.0f) + o1;
        float px = fminf(fmaxf((gx + 1.0f) * ((float)Ww * 0.5f) - 0.5f, 0.0f), (float)(Ww - 1));
        float py = fminf(fmaxf((gy + 1.0f) * ((float)Hh * 0.5f) - 0.5f, 0.0f), (float)(Hh - 1));
        float x0f = floorf(px), y0f = floorf(py);
        float wx = px - x0f, wy = py - y0f;
        int x0 = (int)x0f, y0 = (int)y0f;
        int y1 = min(y0 + 1, Hh - 1);
        const bool hi = (x0 == Ww - 1);
        const int xb = hi ? (Ww - 2) : x0;
        const int r0 = y0 * Ww + xb, r1 = y1 * Ww + xb;
        float rb;
        {
            f2 t0 = *(const f2*)(R + r0);
            f2 t1 = *(const f2*)(R + r1);
            float v00 = hi ? t0.y : t0.x, v01 = t0.y;
            float v10 = hi ? t1.y : t1.x, v11 = t1.y;
            float top = v00 * (1.0f - wx) + v01 * wx;
            float bot = v10 * (1.0f - wx) + v11 * wx;
            rb = top * (1.0f - wy) + bot * wy;
        }
        swx[t] = wx; swy[t] = wy; srb[t] = rb;
        sr0[t] = r0; sr1[t] = r1;
        shi[t] = hi ? 1 : 0;
    }
    __syncthreads();
    {
        const int px = t >> 2, part = t & 3;
        const float wx = swx[px], wy = swy[px], rb = srb[px];
        const bool hi = shi[px] != 0;
        const _Float16* base0 = xnh + ((size_t)b * NPIX + sr0[px]) * Cc + part * 24;
        const _Float16* base1 = xnh + ((size_t)b * NPIX + sr1[px]) * Cc + part * 24;
        float* lp = &lds[px * 97 + part * 24];
        #pragma unroll
        for (int i = 0; i < 3; ++i) {          // 3 x 8 channels
            h8 A = *(const h8*)(base0 + i * 8);
            h8 B = *(const h8*)(base0 + Cc + i * 8);
            h8 C = *(const h8*)(base1 + i * 8);
            h8 D = *(const h8*)(base1 + Cc + i * 8);
            #pragma unroll
            for (int k = 0; k < 8; ++k) {
                float a = (float)A[k], bb = (float)B[k];
                float cc = (float)C[k], dd = (float)D[k];
                float v00 = hi ? bb : a,  v01 = bb;
                float v10 = hi ? dd : cc, v11 = dd;
                float top = v00 * (1.0f - wx) + v01 * wx;
                float bot = v10 * (1.0f - wx) + v11 * wx;
                lp[i * 8 + k] = top * (1.0f - wy) + bot * wy + rb;
            }
        }
    }
    __syncthreads();
    {
        const int jo = t & 63, cq = t >> 6;
        float* ob = out + (size_t)b * Cc * NPIX + jbase + jo;
        const float* lp = &lds[jo * 97 + cq * 24];
        #pragma unroll
        for (int i = 0; i < 24; ++i) {
            const int c = cq * 24 + i;
            ob[(size_t)c * NPIX] = lp[i];
        }
    }
}

// -------------------- K6-FALLBACK: NCHW sampler (f32 x)
__global__ __launch_bounds__(256, 4) void k_sample(const float* __restrict__ x,
        const float* __restrict__ R, const float* __restrict__ offs,
        const int* __restrict__ iperm, float* __restrict__ out) {
    const int lin = blockIdx.x;
    const int swz = (lin & 7) * 128 + (lin >> 3);
    const int tid = threadIdx.x;
    const int b = swz >> 6;
    const int pix = ((swz & 63) << 8) + tid;
    const int hh = pix >> 7, wwp = pix & 127;
    float o0 = offs[(size_t)b * 2 * NPIX + pix];
    float o1 = offs[(size_t)b * 2 * NPIX + NPIX + pix];
    float gx = -1.0f + (float)wwp * (2.0f / 127.0f) + o0;
    float gy = -1.0f + (float)hh * (2.0f / 127.0f) + o1;
    float px = fminf(fmaxf((gx + 1.0f) * ((float)Ww * 0.5f) - 0.5f, 0.0f), (float)(Ww - 1));
    float py = fminf(fmaxf((gy + 1.0f) * ((float)Hh * 0.5f) - 0.5f, 0.0f), (float)(Hh - 1));
    float x0f = floorf(px), y0f = floorf(py);
    float wx = px - x0f, wy = py - y0f;
    int x0 = (int)x0f, y0 = (int)y0f;
    int y1 = min(y0 + 1, Hh - 1);
    const bool hi = (x0 == Ww - 1);
    const int xb = hi ? (Ww - 2) : x0;
    const int r0 = y0 * Ww + xb, r1 = y1 * Ww + xb;
    float rb;
    {
        f2 t0 = *(const f2*)(R + r0);
        f2 t1 = *(const f2*)(R + r1);
        float v00 = hi ? t0.y : t0.x, v01 = t0.y;
        float v10 = hi ? t1.y : t1.x, v11 = t1.y;
        float top = v00 * (1.0f - wx) + v01 * wx;
        float bot = v10 * (1.0f - wx) + v11 * wx;
        rb = top * (1.0f - wy) + bot * wy;
    }
    const int c0 = blockIdx.y * CPG;
    const int j = iperm[(size_t)b * NPIX + pix];
    const float* xp = x + (size_t)b * Cc * NPIX + (size_t)c0 * NPIX;
    float* op = out + (size_t)b * Cc * NPIX + (size_t)c0 * NPIX + j;
    f2 t0[CPG], t1[CPG];
    #pragma unroll
    for (int c = 0; c < CPG; ++c) {
        const float* xc = xp + (size_t)c * NPIX;
        t0[c] = *(const f2*)(xc + r0);
        t1[c] = *(const f2*)(xc + r1);
    }
    #pragma unroll
    for (int c = 0; c < CPG; ++c) {
        float v00 = hi ? t0[c].y : t0[c].x, v01 = t0[c].y;
        float v10 = hi ? t1[c].y : t1[c].x, v11 = t1[c].y;
        float top = v00 * (1.0f - wx) + v01 * wx;
        float bot = v10 * (1.0f - wx) + v11 * wx;
        op[(size_t)c * NPIX] = top * (1.0f - wy) + bot * wy + rb;
    }
}

// fallback-path group kernel (used only when ws too small for xnh)
__global__ __launch_bounds__(256) void k_group(const float* __restrict__ x,
        const float* __restrict__ centers, int* __restrict__ gid) {
    __shared__ double scn[Mm * Cc];
    const int tid = threadIdx.x;
    for (int i = tid; i < Mm * Cc; i += 256) scn[i] = (double)centers[i];
    __syncthreads();
    if (tid < Mm) {
        double ss = 0.0;
        #pragma unroll
        for (int c = 0; c < Cc; ++c) { double v = scn[tid * Cc + c]; ss += v * v; }
        double inv = 1.0 / fmax(sqrt(ss), 1e-12);
        #pragma unroll
        for (int c = 0; c < Cc; ++c) scn[tid * Cc + c] *= inv;
    }
    __syncthreads();
    const int b = blockIdx.x >> 6;
    const int n = ((blockIdx.x & 63) << 8) + tid;
    const float* xp = x + (size_t)b * Cc * NPIX + n;
    double acc[Mm];
    #pragma unroll
    for (int m = 0; m < Mm; ++m) acc[m] = 0.0;
    for (int c = 0; c < Cc; ++c) {
        double xv = (double)xp[(size_t)c * NPIX];
        #pragma unroll
        for (int m = 0; m < Mm; ++m) acc[m] = fma(xv, scn[m * Cc + c], acc[m]);
    }
    int bi = 0;
    double bv = acc[0];
    #pragma unroll
    for (int m = 1; m < Mm; ++m) {
        if (acc[m] > bv) { bv = acc[m]; bi = m; }
    }
    gid[(size_t)b * NPIX + n] = bi;
}

// fallback attn (only for ws-too-small path)
__global__ void k_attn(const float* __restrict__ partial,
        const float* __restrict__ ca_w1, const float* __restrict__ ca_w2,
        float* __restrict__ attnout) {
    __shared__ float pm[Cc];
    __shared__ float hh[CR];
    const int tid = threadIdx.x;
    const int b = blockIdx.x;
    if (tid < Cc) {
        float s = 0.f;
        const float* p = partial + (b * Cc + tid) * 8;
        #pragma unroll
        for (int i = 0; i < 8; ++i) s += p[i];
        pm[tid] = s * (1.0f / (float)NPIX);
    }
    __syncthreads();
    if (tid < CR) {
        float s = 0.f;
        for (int c0 = 0; c0 < Cc; ++c0) s = fmaf(ca_w1[tid * Cc + c0], pm[c0], s);
        hh[tid] = fmaxf(s, 0.f);
    }
    __syncthreads();
    if (tid < Cc) {
        float s = 0.f;
        #pragma unroll
        for (int r = 0; r < CR; ++r) s = fmaf(ca_w2[tid * CR + r], hh[r], s);
        attnout[b * Cc + tid] = 1.0f / (1.0f + expf(-s));
    }
}

extern "C" void kernel_launch(void* const* d_in, const int* in_sizes, int n_in,
                              void* d_out, int out_size, void* d_ws, size_t ws_size,
                              hipStream_t stream) {
    const float* x       = (const float*)d_in[0];
    const float* dw_w    = (const float*)d_in[1];
    const float* dw_b    = (const float*)d_in[2];
    const float* ca_w1   = (const float*)d_in[3];
    const float* ca_w2   = (const float*)d_in[4];
    const float* ln_g    = (const float*)d_in[5];
    const float* ln_b    = (const float*)d_in[6];
    const float* off_w   = (const float*)d_in[7];
    const float* R       = (const float*)d_in[8];
    const float* centers = (const float*)d_in[9];
    float* out = (float*)d_out;

    // workspace: small region (~5.3MB) + optional f16 xnh (50.3MB)
    float* partial = (float*)d_ws;                 // Bc*Cc*8
    float* attn    = partial + Bc * Cc * 8;        // Bc*Cc (fallback path only)
    float* offs    = attn + Bc * Cc;               // Bc*2*NPIX
    int*   gid     = (int*)(offs + Bc * 2 * NPIX); // Bc*NPIX
    int*   iperm   = gid + Bc * NPIX;              // Bc*NPIX
    int*   permi   = iperm + Bc * NPIX;            // Bc*NPIX
    _Float16* xnh  = (_Float16*)(permi + Bc * NPIX); // Bc*NPIX*Cc f16 (optional)

    const size_t small_elems = (size_t)Bc * Cc * 8 + Bc * Cc +
                               (size_t)Bc * 2 * NPIX + 3 * (size_t)Bc * NPIX;
    const size_t need = small_elems * 4 + (size_t)Bc * NPIX * Cc * 2;
    const int do_nhwc = (ws_size >= need) ? 1 : 0;

    // conv output f lives (as f16) in out's map region; dead after ln_off,
    // then overwritten by the sampler's f32 writes.
    _Float16* f = (_Float16*)out;

    hipLaunchKernelGGL(k_conv, dim3(Ww / CTW, Hh / CTH, Bc * Cc), dim3(256), 0,
                       stream, x, dw_w, dw_b, f, partial);
    if (do_nhwc) {
        hipLaunchKernelGGL(k_ln_off, dim3(1024), dim3(256), 0, stream,
                           f, partial, ca_w1, ca_w2, ln_g, ln_b, off_w, offs);
        hipLaunchKernelGGL(k_trg, dim3(2048), dim3(256), 0, stream,
                           x, centers, xnh, gid);
        hipLaunchKernelGGL(k_sort, dim3(Bc), dim3(256), 0, stream,
                           gid, centers, iperm, permi, out);
        hipLaunchKernelGGL(k_sample_nhwc, dim3(4096), dim3(256), 0, stream,
                           xnh, R, offs, permi, out);
    } else {
        hipLaunchKernelGGL(k_ln_off, dim3(1024), dim3(256), 0, stream,
                           f, partial, ca_w1, ca_w2, ln_g, ln_b, off_w, offs);
        hipLaunchKernelGGL(k_group, dim3(1024), dim3(256), 0, stream,
                           x, centers, gid);
        hipLaunchKernelGGL(k_sort, dim3(Bc), dim3(256), 0, stream,
                           gid, centers, iperm, permi, out);
        hipLaunchKernelGGL(k_sample, dim3(1024, CGROUPS), dim3(256), 0, stream,
                           x, R, offs, iperm, out);
    }
}

// Round 22
// 202.249 us; speedup vs baseline: 1.9505x; 1.9505x over previous
//
#include <hip/hip_runtime.h>
#include <math.h>
#include <stdint.h>

#define Bc 16
#define Cc 96
#define Hh 128
#define Ww 128
#define NPIX 16384
#define Mm 12
#define CR 6
#define PAD 3

// conv tile geometry: f16 LDS tile, stride 80 f16 (160B rows).
#define CTH 32
#define CTW 64
#define TROWS 38
#define TCOLS2 72          // staged cols
#define TSH 80             // f16 stride

// fallback k_sample channel split
#define CGROUPS 6
#define CPG 16

typedef float f2 __attribute__((ext_vector_type(2), aligned(4)));
typedef _Float16 h8 __attribute__((ext_vector_type(8)));   // 16B f16 vector
typedef _Float16 h2 __attribute__((ext_vector_type(2)));   // packed f16 pair

union HU { uint32_t u; h2 h; };
union H8U { h8 v; uint32_t u[4]; };

// -------------------- K1: depthwise 7x7 conv + bias (packed-f16 inner loop)
__global__ __launch_bounds__(256) void k_conv(const float* __restrict__ x,
        const float* __restrict__ dw_w, const float* __restrict__ dw_b,
        _Float16* __restrict__ f, float* __restrict__ partial) {
    const int bc = blockIdx.z;
    const int c = bc % Cc;
    __shared__ _Float16 tile[TROWS * TSH];
    __shared__ uint32_t wp2[49];           // f16 splat-pairs {w,w}
    __shared__ float red[256];
    const int tid = threadIdx.x;
    if (tid < 49) {
        _Float16 wh = (_Float16)dw_w[c * 49 + tid];
        HU u; u.h = (h2){wh, wh};
        wp2[tid] = u.u;
    }
    const int ox0 = blockIdx.x * CTW, oy0 = blockIdx.y * CTH;
    const float* xp = x + (size_t)bc * NPIX;
    for (int i = tid; i < TROWS * TCOLS2; i += 256) {
        int r = i / TCOLS2, cc2 = i % TCOLS2;
        int gy = oy0 + r - PAD, gx = ox0 + cc2 - PAD;
        float v = 0.f;
        if (gy >= 0 && gy < Hh && gx >= 0 && gx < Ww) v = xp[gy * Ww + gx];
        tile[r * TSH + cc2] = (_Float16)v;
    }
    __syncthreads();
    const int tx = tid & 7;
    const int ty = tid >> 3;
    const _Float16 biash = (_Float16)dw_b[c];
    h2 acc2[4];
    #pragma unroll
    for (int p = 0; p < 4; ++p) acc2[p] = (h2){biash, biash};
    #pragma unroll
    for (int ky = 0; ky < 7; ++ky) {
        const _Float16* rowp = &tile[(ty + ky) * TSH + tx * 8];
        H8U A, B;
        A.v = *(const h8*)(rowp);
        B.v = *(const h8*)(rowp + 8);
        uint32_t pm[13];
        pm[0]  = A.u[0];
        pm[2]  = A.u[1];
        pm[4]  = A.u[2];
        pm[6]  = A.u[3];
        pm[8]  = B.u[0];
        pm[10] = B.u[1];
        pm[12] = B.u[2];
        pm[1]  = (A.u[0] >> 16) | (A.u[1] << 16);
        pm[3]  = (A.u[1] >> 16) | (A.u[2] << 16);
        pm[5]  = (A.u[2] >> 16) | (A.u[3] << 16);
        pm[7]  = (A.u[3] >> 16) | (B.u[0] << 16);
        pm[9]  = (B.u[0] >> 16) | (B.u[1] << 16);
        pm[11] = (B.u[1] >> 16) | (B.u[2] << 16);
        #pragma unroll
        for (int kx = 0; kx < 7; ++kx) {
            HU w; w.u = wp2[ky * 7 + kx];
            #pragma unroll
            for (int p = 0; p < 4; ++p) {
                HU m; m.u = pm[kx + 2 * p];
                acc2[p] = m.h * w.h + acc2[p];    // v_pk_fma_f16
            }
        }
    }
    _Float16* op = f + (size_t)bc * NPIX + (oy0 + ty) * Ww + ox0 + tx * 8;
    h8 o;
    #pragma unroll
    for (int p = 0; p < 4; ++p) {
        o[2 * p] = acc2[p].x;
        o[2 * p + 1] = acc2[p].y;
    }
    *(h8*)op = o;
    float s = 0.f;
    #pragma unroll
    for (int p = 0; p < 4; ++p)
        s += (float)acc2[p].x + (float)acc2[p].y;
    red[tid] = s;
    __syncthreads();
    for (int st = 128; st > 0; st >>= 1) {
        if (tid < st) red[tid] += red[tid + st];
        __syncthreads();
    }
    if (tid == 0) partial[bc * 8 + blockIdx.y * 2 + blockIdx.x] = red[0];
}

// fast erf (A&S 7.1.26, |err|<=1.5e-7)
__device__ __forceinline__ float fast_gelu(float v) {
    float z = fabsf(v) * 0.70710678118654752440f;
    float t = 1.0f / fmaf(0.3275911f, z, 1.0f);
    float poly = t * fmaf(t, fmaf(t, fmaf(t, fmaf(t, 1.061405429f, -1.453152027f),
                          1.421413741f), -0.284496736f), 0.254829592f);
    float e = exp2f(-1.44269504088896340736f * z * z);
    float erfz = 1.0f - poly * e;
    erfz = (v < 0.0f) ? -erfz : erfz;
    return 0.5f * v * (1.0f + erfz);
}

// -------------------- K3: fused SE-attn + GELU + LN + offset proj
// r20/r21 lesson: don't fight the register allocator — change decomposition.
// Block = 64 pixels x 4 channel-groups of 24. Each thread holds u[24] only
// (VGPR ~56), partial s1/s2 LDS-reduced across groups (fixed order ->
// deterministic), then per-group o0/o1 partials reduced the same way.
// Lanes 0..63 = consecutive pixels at same channel -> coalesced loads.
__global__ __launch_bounds__(256) void k_ln_off(const _Float16* __restrict__ f,
        const float* __restrict__ partial, const float* __restrict__ ca_w1,
        const float* __restrict__ ca_w2, const float* __restrict__ ln_g,
        const float* __restrict__ ln_b, const float* __restrict__ off_w,
        float* __restrict__ offs) {
    __shared__ float pm[Cc], hh[CR];
    __shared__ float sa[Cc], sg[Cc], sb[Cc], sw0[Cc], sw1[Cc];
    __shared__ float red1[4][64], red2[4][64];
    const int t = threadIdx.x;
    const int b = blockIdx.x >> 8;               // 4096 blocks: 256 per batch
    const int pixbase = (blockIdx.x & 255) * 64;
    const int po = t & 63;                       // pixel offset 0..63
    const int cg = t >> 6;                       // channel group 0..3
    const int pix = pixbase + po;
    if (t < Cc) {
        float s = 0.f;
        const float* p = partial + (b * Cc + t) * 8;
        #pragma unroll
        for (int i = 0; i < 8; ++i) s += p[i];
        pm[t] = s * (1.0f / (float)NPIX);
        sg[t] = ln_g[t];
        sb[t] = ln_b[t];
        sw0[t] = off_w[t];
        sw1[t] = off_w[Cc + t];
    }
    __syncthreads();
    if (t < CR) {
        float s = 0.f;
        for (int c0 = 0; c0 < Cc; ++c0) s = fmaf(ca_w1[t * Cc + c0], pm[c0], s);
        hh[t] = fmaxf(s, 0.f);
    }
    __syncthreads();
    if (t < Cc) {
        float s = 0.f;
        #pragma unroll
        for (int r = 0; r < CR; ++r) s = fmaf(ca_w2[t * CR + r], hh[r], s);
        sa[t] = 1.0f / (1.0f + expf(-s));
    }
    __syncthreads();
    const _Float16* fp = f + (size_t)b * Cc * NPIX + pix;
    float u[24];
    float s1 = 0.f, s2 = 0.f;
    #pragma unroll
    for (int i = 0; i < 24; ++i) {
        const int c = cg * 24 + i;
        float g = fast_gelu((float)fp[(size_t)c * NPIX] * sa[c]);
        u[i] = g;
        s1 += g;
        s2 = fmaf(g, g, s2);
    }
    red1[cg][po] = s1;
    red2[cg][po] = s2;
    __syncthreads();
    const float S1 = ((red1[0][po] + red1[1][po]) + (red1[2][po] + red1[3][po]));
    const float S2 = ((red2[0][po] + red2[1][po]) + (red2[2][po] + red2[3][po]));
    const float mu = S1 * (1.0f / (float)Cc);
    const float var = fmaxf(S2 * (1.0f / (float)Cc) - mu * mu, 0.f);
    const float rs = rsqrtf(var + 1e-5f);
    __syncthreads();                              // readers done before rewrite
    float o0 = 0.f, o1 = 0.f;
    #pragma unroll
    for (int i = 0; i < 24; ++i) {
        const int c = cg * 24 + i;
        float v = (u[i] - mu) * rs * sg[c] + sb[c];
        o0 = fmaf(sw0[c], v, o0);
        o1 = fmaf(sw1[c], v, o1);
    }
    red1[cg][po] = o0;
    red2[cg][po] = o1;
    __syncthreads();
    if (cg == 0) {
        float O0 = ((red1[0][po] + red1[1][po]) + (red1[2][po] + red1[3][po]));
        float O1 = ((red2[0][po] + red2[1][po]) + (red2[2][po] + red2[3][po]));
        offs[(size_t)b * 2 * NPIX + pix] = O0;
        offs[(size_t)b * 2 * NPIX + NPIX + pix] = O1;
    }
}

// -------------------- K-TRG: fused NCHW->NHWC(f16) transpose + FP64 argmax
__global__ __launch_bounds__(256) void k_trg(const float* __restrict__ x,
        const float* __restrict__ centers, _Float16* __restrict__ xnh,
        int* __restrict__ gid) {
    __shared__ float lds[Cc * 129];
    __shared__ double scn[Mm * Cc];
    __shared__ double pacc[Mm * 129];
    const int bid = blockIdx.x;                // 0..2047
    const int b = bid >> 7;
    const int p0 = (bid & 127) * 128;
    const int t = threadIdx.x;
    const int px = t & 127, crow = t >> 7;
    const float* xp = x + (size_t)b * Cc * NPIX + p0 + px;
    #pragma unroll
    for (int it = 0; it < 48; ++it) {
        const int c = it * 2 + crow;
        lds[c * 129 + px] = xp[(size_t)c * NPIX];
    }
    if (t < Mm) {
        double ss = 0.0;
        #pragma unroll
        for (int c = 0; c < Cc; ++c) {
            double v = (double)centers[t * Cc + c];
            ss += v * v;
        }
        double inv = 1.0 / fmax(sqrt(ss), 1e-12);
        #pragma unroll
        for (int c = 0; c < Cc; ++c)
            scn[t * Cc + c] = (double)centers[t * Cc + c] * inv;
    }
    __syncthreads();
    _Float16* ob = xnh + ((size_t)b * NPIX + p0) * Cc;
    #pragma unroll
    for (int i = 0; i < 6; ++i) {
        const int idx = i * 256 + t;           // 0..1535
        const int gpos = idx * 8;              // f16 index in strip (12288)
        const int ppx = gpos / 96;
        const int c = gpos - ppx * 96;         // multiple of 8
        h8 v;
        #pragma unroll
        for (int k = 0; k < 8; ++k)
            v[k] = (_Float16)lds[(c + k) * 129 + ppx];
        *(h8*)(ob + gpos) = v;
    }
    const int c0 = crow * 48;
    double acc[Mm];
    #pragma unroll
    for (int m = 0; m < Mm; ++m) acc[m] = 0.0;
    for (int cc2 = 0; cc2 < 48; ++cc2) {
        const int c = c0 + cc2;
        double xv = (double)lds[c * 129 + px];
        #pragma unroll
        for (int m = 0; m < Mm; ++m)
            acc[m] = fma(xv, scn[m * Cc + c], acc[m]);
    }
    if (crow == 1) {
        #pragma unroll
        for (int m = 0; m < Mm; ++m) pacc[m * 129 + px] = acc[m];
    }
    __syncthreads();
    if (crow == 0) {
        int bi = 0;
        double bv = acc[0] + pacc[0 * 129 + px];
        #pragma unroll
        for (int m = 1; m < Mm; ++m) {
            double v = acc[m] + pacc[m * 129 + px];
            if (v > bv) { bv = v; bi = m; }
        }
        gid[(size_t)b * NPIX + p0 + px] = bi;
    }
}

// -------------------- K5: stable counting sort; + centers copy (block 0)
__global__ __launch_bounds__(256) void k_sort(const int* __restrict__ gid,
        const float* __restrict__ centers, int* __restrict__ iperm,
        int* __restrict__ permi, float* __restrict__ out) {
    __shared__ int hist[256 * Mm];
    __shared__ int tot[Mm];
    const int t = threadIdx.x;
    const int b = blockIdx.x;
    if (b == 0) {  // centers copy (output 2)
        const size_t base = (size_t)Bc * Cc * NPIX + (size_t)Bc * NPIX;
        for (int i = t; i < Mm * Cc; i += 256) out[base + i] = centers[i];
    }
    for (int i = t; i < 256 * Mm; i += 256) hist[i] = 0;
    __syncthreads();
    const int* gp = gid + (size_t)b * NPIX;
    const int base = t * 64;
    for (int i = 0; i < 64; ++i) hist[t * Mm + gp[base + i]] += 1;
    __syncthreads();
    if (t < Mm) {
        int run = 0;
        for (int r = 0; r < 256; ++r) {
            int v = hist[r * Mm + t];
            hist[r * Mm + t] = run;
            run += v;
        }
        tot[t] = run;
    }
    __syncthreads();
    if (t == 0) {
        int run = 0;
        for (int m = 0; m < Mm; ++m) { int v = tot[m]; tot[m] = run; run += v; }
    }
    __syncthreads();
    int* ip = iperm + (size_t)b * NPIX;
    int* pi = permi + (size_t)b * NPIX;
    float* fperm = out + (size_t)Bc * Cc * NPIX + (size_t)b * NPIX;
    for (int i = 0; i < 64; ++i) {
        int src = base + i;
        int g = gp[src];
        int pos = tot[g] + hist[t * Mm + g];
        hist[t * Mm + g] += 1;
        ip[src] = pos;
        pi[pos] = src;
        fperm[pos] = (float)src;
    }
}

// -------------------- K6-FAST: output-position-ordered f16-NHWC sampler
__global__ __launch_bounds__(256) void k_sample_nhwc(
        const _Float16* __restrict__ xnh, const float* __restrict__ R,
        const float* __restrict__ offs, const int* __restrict__ permi,
        float* __restrict__ out) {
    const int lin = blockIdx.x;                    // 0..4095
    const int swz = (lin & 7) * 512 + (lin >> 3);  // 2 batches per XCD
    const int b = swz >> 8;
    const int jbase = (swz & 255) * 64;
    __shared__ float lds[64 * 97];
    __shared__ float swx[64], swy[64], srb[64];
    __shared__ int sr0[64], sr1[64], shi[64];
    const int t = threadIdx.x;
    if (t < 64) {
        const int src = permi[(size_t)b * NPIX + jbase + t];
        const int hh = src >> 7, wwp = src & 127;
        float o0 = offs[(size_t)b * 2 * NPIX + src];
        float o1 = offs[(size_t)b * 2 * NPIX + NPIX + src];
        float gx = -1.0f + (float)wwp * (2.0f / 127.0f) + o0;
        float gy = -1.0f + (float)hh * (2.0f / 127.0f) + o1;
        float px = fminf(fmaxf((gx + 1.0f) * ((float)Ww * 0.5f) - 0.5f, 0.0f), (float)(Ww - 1));
        float py = fminf(fmaxf((gy + 1.0f) * ((float)Hh * 0.5f) - 0.5f, 0.0f), (float)(Hh - 1));
        float x0f = floorf(px), y0f = floorf(py);
        float wx = px - x0f, wy = py - y0f;
        int x0 = (int)x0f, y0 = (int)y0f;
        int y1 = min(y0 + 1, Hh - 1);
        const bool hi = (x0 == Ww - 1);
        const int xb = hi ? (Ww - 2) : x0;
        const int r0 = y0 * Ww + xb, r1 = y1 * Ww + xb;
        float rb;
        {
            f2 t0 = *(const f2*)(R + r0);
            f2 t1 = *(const f2*)(R + r1);
            float v00 = hi ? t0.y : t0.x, v01 = t0.y;
            float v10 = hi ? t1.y : t1.x, v11 = t1.y;
            float top = v00 * (1.0f - wx) + v01 * wx;
            float bot = v10 * (1.0f - wx) + v11 * wx;
            rb = top * (1.0f - wy) + bot * wy;
        }
        swx[t] = wx; swy[t] = wy; srb[t] = rb;
        sr0[t] = r0; sr1[t] = r1;
        shi[t] = hi ? 1 : 0;
    }
    __syncthreads();
    {
        const int px = t >> 2, part = t & 3;
        const float wx = swx[px], wy = swy[px], rb = srb[px];
        const bool hi = shi[px] != 0;
        const _Float16* base0 = xnh + ((size_t)b * NPIX + sr0[px]) * Cc + part * 24;
        const _Float16* base1 = xnh + ((size_t)b * NPIX + sr1[px]) * Cc + part * 24;
        float* lp = &lds[px * 97 + part * 24];
        #pragma unroll
        for (int i = 0; i < 3; ++i) {          // 3 x 8 channels
            h8 A = *(const h8*)(base0 + i * 8);
            h8 B = *(const h8*)(base0 + Cc + i * 8);
            h8 C = *(const h8*)(base1 + i * 8);
            h8 D = *(const h8*)(base1 + Cc + i * 8);
            #pragma unroll
            for (int k = 0; k < 8; ++k) {
                float a = (float)A[k], bb = (float)B[k];
                float cc = (float)C[k], dd = (float)D[k];
                float v00 = hi ? bb : a,  v01 = bb;
                float v10 = hi ? dd : cc, v11 = dd;
                float top = v00 * (1.0f - wx) + v01 * wx;
                float bot = v10 * (1.0f - wx) + v11 * wx;
                lp[i * 8 + k] = top * (1.0f - wy) + bot * wy + rb;
            }
        }
    }
    __syncthreads();
    {
        const int jo = t & 63, cq = t >> 6;
        float* ob = out + (size_t)b * Cc * NPIX + jbase + jo;
        const float* lp = &lds[jo * 97 + cq * 24];
        #pragma unroll
        for (int i = 0; i < 24; ++i) {
            const int c = cq * 24 + i;
            ob[(size_t)c * NPIX] = lp[i];
        }
    }
}

// -------------------- K6-FALLBACK: NCHW sampler (f32 x)
__global__ __launch_bounds__(256, 4) void k_sample(const float* __restrict__ x,
        const float* __restrict__ R, const float* __restrict__ offs,
        const int* __restrict__ iperm, float* __restrict__ out) {
    const int lin = blockIdx.x;
    const int swz = (lin & 7) * 128 + (lin >> 3);
    const int tid = threadIdx.x;
    const int b = swz >> 6;
    const int pix = ((swz & 63) << 8) + tid;
    const int hh = pix >> 7, wwp = pix & 127;
    float o0 = offs[(size_t)b * 2 * NPIX + pix];
    float o1 = offs[(size_t)b * 2 * NPIX + NPIX + pix];
    float gx = -1.0f + (float)wwp * (2.0f / 127.0f) + o0;
    float gy = -1.0f + (float)hh * (2.0f / 127.0f) + o1;
    float px = fminf(fmaxf((gx + 1.0f) * ((float)Ww * 0.5f) - 0.5f, 0.0f), (float)(Ww - 1));
    float py = fminf(fmaxf((gy + 1.0f) * ((float)Hh * 0.5f) - 0.5f, 0.0f), (float)(Hh - 1));
    float x0f = floorf(px), y0f = floorf(py);
    float wx = px - x0f, wy = py - y0f;
    int x0 = (int)x0f, y0 = (int)y0f;
    int y1 = min(y0 + 1, Hh - 1);
    const bool hi = (x0 == Ww - 1);
    const int xb = hi ? (Ww - 2) : x0;
    const int r0 = y0 * Ww + xb, r1 = y1 * Ww + xb;
    float rb;
    {
        f2 t0 = *(const f2*)(R + r0);
        f2 t1 = *(const f2*)(R + r1);
        float v00 = hi ? t0.y : t0.x, v01 = t0.y;
        float v10 = hi ? t1.y : t1.x, v11 = t1.y;
        float top = v00 * (1.0f - wx) + v01 * wx;
        float bot = v10 * (1.0f - wx) + v11 * wx;
        rb = top * (1.0f - wy) + bot * wy;
    }
    const int c0 = blockIdx.y * CPG;
    const int j = iperm[(size_t)b * NPIX + pix];
    const float* xp = x + (size_t)b * Cc * NPIX + (size_t)c0 * NPIX;
    float* op = out + (size_t)b * Cc * NPIX + (size_t)c0 * NPIX + j;
    f2 t0[CPG], t1[CPG];
    #pragma unroll
    for (int c = 0; c < CPG; ++c) {
        const float* xc = xp + (size_t)c * NPIX;
        t0[c] = *(const f2*)(xc + r0);
        t1[c] = *(const f2*)(xc + r1);
    }
    #pragma unroll
    for (int c = 0; c < CPG; ++c) {
        float v00 = hi ? t0[c].y : t0[c].x, v01 = t0[c].y;
        float v10 = hi ? t1[c].y : t1[c].x, v11 = t1[c].y;
        float top = v00 * (1.0f - wx) + v01 * wx;
        float bot = v10 * (1.0f - wx) + v11 * wx;
        op[(size_t)c * NPIX] = top * (1.0f - wy) + bot * wy + rb;
    }
}

// fallback-path group kernel (used only when ws too small for xnh)
__global__ __launch_bounds__(256) void k_group(const float* __restrict__ x,
        const float* __restrict__ centers, int* __restrict__ gid) {
    __shared__ double scn[Mm * Cc];
    const int tid = threadIdx.x;
    for (int i = tid; i < Mm * Cc; i += 256) scn[i] = (double)centers[i];
    __syncthreads();
    if (tid < Mm) {
        double ss = 0.0;
        #pragma unroll
        for (int c = 0; c < Cc; ++c) { double v = scn[tid * Cc + c]; ss += v * v; }
        double inv = 1.0 / fmax(sqrt(ss), 1e-12);
        #pragma unroll
        for (int c = 0; c < Cc; ++c) scn[tid * Cc + c] *= inv;
    }
    __syncthreads();
    const int b = blockIdx.x >> 6;
    const int n = ((blockIdx.x & 63) << 8) + tid;
    const float* xp = x + (size_t)b * Cc * NPIX + n;
    double acc[Mm];
    #pragma unroll
    for (int m = 0; m < Mm; ++m) acc[m] = 0.0;
    for (int c = 0; c < Cc; ++c) {
        double xv = (double)xp[(size_t)c * NPIX];
        #pragma unroll
        for (int m = 0; m < Mm; ++m) acc[m] = fma(xv, scn[m * Cc + c], acc[m]);
    }
    int bi = 0;
    double bv = acc[0];
    #pragma unroll
    for (int m = 1; m < Mm; ++m) {
        if (acc[m] > bv) { bv = acc[m]; bi = m; }
    }
    gid[(size_t)b * NPIX + n] = bi;
}

// fallback attn (only for ws-too-small path)
__global__ void k_attn(const float* __restrict__ partial,
        const float* __restrict__ ca_w1, const float* __restrict__ ca_w2,
        float* __restrict__ attnout) {
    __shared__ float pm[Cc];
    __shared__ float hh[CR];
    const int tid = threadIdx.x;
    const int b = blockIdx.x;
    if (tid < Cc) {
        float s = 0.f;
        const float* p = partial + (b * Cc + tid) * 8;
        #pragma unroll
        for (int i = 0; i < 8; ++i) s += p[i];
        pm[tid] = s * (1.0f / (float)NPIX);
    }
    __syncthreads();
    if (tid < CR) {
        float s = 0.f;
        for (int c0 = 0; c0 < Cc; ++c0) s = fmaf(ca_w1[tid * Cc + c0], pm[c0], s);
        hh[tid] = fmaxf(s, 0.f);
    }
    __syncthreads();
    if (tid < Cc) {
        float s = 0.f;
        #pragma unroll
        for (int r = 0; r < CR; ++r) s = fmaf(ca_w2[tid * CR + r], hh[r], s);
        attnout[b * Cc + tid] = 1.0f / (1.0f + expf(-s));
    }
}

extern "C" void kernel_launch(void* const* d_in, const int* in_sizes, int n_in,
                              void* d_out, int out_size, void* d_ws, size_t ws_size,
                              hipStream_t stream) {
    const float* x       = (const float*)d_in[0];
    const float* dw_w    = (const float*)d_in[1];
    const float* dw_b    = (const float*)d_in[2];
    const float* ca_w1   = (const float*)d_in[3];
    const float* ca_w2   = (const float*)d_in[4];
    const float* ln_g    = (const float*)d_in[5];
    const float* ln_b    = (const float*)d_in[6];
    const float* off_w   = (const float*)d_in[7];
    const float* R       = (const float*)d_in[8];
    const float* centers = (const float*)d_in[9];
    float* out = (float*)d_out;

    // workspace: small region (~5.3MB) + optional f16 xnh (50.3MB)
    float* partial = (float*)d_ws;                 // Bc*Cc*8
    float* attn    = partial + Bc * Cc * 8;        // Bc*Cc (fallback path only)
    float* offs    = attn + Bc * Cc;               // Bc*2*NPIX
    int*   gid     = (int*)(offs + Bc * 2 * NPIX); // Bc*NPIX
    int*   iperm   = gid + Bc * NPIX;              // Bc*NPIX
    int*   permi   = iperm + Bc * NPIX;            // Bc*NPIX
    _Float16* xnh  = (_Float16*)(permi + Bc * NPIX); // Bc*NPIX*Cc f16 (optional)

    const size_t small_elems = (size_t)Bc * Cc * 8 + Bc * Cc +
                               (size_t)Bc * 2 * NPIX + 3 * (size_t)Bc * NPIX;
    const size_t need = small_elems * 4 + (size_t)Bc * NPIX * Cc * 2;
    const int do_nhwc = (ws_size >= need) ? 1 : 0;

    // conv output f lives (as f16) in out's map region; dead after ln_off,
    // then overwritten by the sampler's f32 writes.
    _Float16* f = (_Float16*)out;

    hipLaunchKernelGGL(k_conv, dim3(Ww / CTW, Hh / CTH, Bc * Cc), dim3(256), 0,
                       stream, x, dw_w, dw_b, f, partial);
    if (do_nhwc) {
        hipLaunchKernelGGL(k_ln_off, dim3(4096), dim3(256), 0, stream,
                           f, partial, ca_w1, ca_w2, ln_g, ln_b, off_w, offs);
        hipLaunchKernelGGL(k_trg, dim3(2048), dim3(256), 0, stream,
                           x, centers, xnh, gid);
        hipLaunchKernelGGL(k_sort, dim3(Bc), dim3(256), 0, stream,
                           gid, centers, iperm, permi, out);
        hipLaunchKernelGGL(k_sample_nhwc, dim3(4096), dim3(256), 0, stream,
                           xnh, R, offs, permi, out);
    } else {
        hipLaunchKernelGGL(k_ln_off, dim3(4096), dim3(256), 0, stream,
                           f, partial, ca_w1, ca_w2, ln_g, ln_b, off_w, offs);
        hipLaunchKernelGGL(k_group, dim3(1024), dim3(256), 0, stream,
                           x, centers, gid);
        hipLaunchKernelGGL(k_sort, dim3(Bc), dim3(256), 0, stream,
                           gid, centers, iperm, permi, out);
        hipLaunchKernelGGL(k_sample, dim3(1024, CGROUPS), dim3(256), 0, stream,
                           x, R, offs, iperm, out);
    }
}

// Round 23
// 200.741 us; speedup vs baseline: 1.9651x; 1.0075x over previous
//
#include <hip/hip_runtime.h>
#include <math.h>
#include <stdint.h>

#define Bc 16
#define Cc 96
#define Hh 128
#define Ww 128
#define NPIX 16384
#define Mm 12
#define CR 6
#define PAD 3

// conv tile geometry: f16 LDS tile, stride 80 f16 (160B rows).
#define CTH 32
#define CTW 64
#define TROWS 38
#define TCOLS2 72          // staged cols
#define TSH 80             // f16 stride

// fallback k_sample channel split
#define CGROUPS 6
#define CPG 16

typedef float f2 __attribute__((ext_vector_type(2), aligned(4)));
typedef _Float16 h8 __attribute__((ext_vector_type(8)));   // 16B f16 vector
typedef _Float16 h2 __attribute__((ext_vector_type(2)));   // packed f16 pair

union HU { uint32_t u; h2 h; };
union H8U { h8 v; uint32_t u[4]; };

// -------------------- K1: depthwise 7x7 conv + bias (packed-f16 inner loop)
// Pool partial via wave-shuffle reduce (deterministic, 1 barrier) instead of
// the 8-barrier tree: 7 fewer sync points per block x 12288 blocks.
__global__ __launch_bounds__(256) void k_conv(const float* __restrict__ x,
        const float* __restrict__ dw_w, const float* __restrict__ dw_b,
        _Float16* __restrict__ f, float* __restrict__ partial) {
    const int bc = blockIdx.z;
    const int c = bc % Cc;
    __shared__ _Float16 tile[TROWS * TSH];
    __shared__ uint32_t wp2[49];           // f16 splat-pairs {w,w}
    __shared__ float red[4];
    const int tid = threadIdx.x;
    if (tid < 49) {
        _Float16 wh = (_Float16)dw_w[c * 49 + tid];
        HU u; u.h = (h2){wh, wh};
        wp2[tid] = u.u;
    }
    const int ox0 = blockIdx.x * CTW, oy0 = blockIdx.y * CTH;
    const float* xp = x + (size_t)bc * NPIX;
    for (int i = tid; i < TROWS * TCOLS2; i += 256) {
        int r = i / TCOLS2, cc2 = i % TCOLS2;
        int gy = oy0 + r - PAD, gx = ox0 + cc2 - PAD;
        float v = 0.f;
        if (gy >= 0 && gy < Hh && gx >= 0 && gx < Ww) v = xp[gy * Ww + gx];
        tile[r * TSH + cc2] = (_Float16)v;
    }
    __syncthreads();
    const int tx = tid & 7;
    const int ty = tid >> 3;
    const _Float16 biash = (_Float16)dw_b[c];
    h2 acc2[4];
    #pragma unroll
    for (int p = 0; p < 4; ++p) acc2[p] = (h2){biash, biash};
    #pragma unroll
    for (int ky = 0; ky < 7; ++ky) {
        const _Float16* rowp = &tile[(ty + ky) * TSH + tx * 8];
        H8U A, B;
        A.v = *(const h8*)(rowp);
        B.v = *(const h8*)(rowp + 8);
        uint32_t pm[13];
        pm[0]  = A.u[0];
        pm[2]  = A.u[1];
        pm[4]  = A.u[2];
        pm[6]  = A.u[3];
        pm[8]  = B.u[0];
        pm[10] = B.u[1];
        pm[12] = B.u[2];
        pm[1]  = (A.u[0] >> 16) | (A.u[1] << 16);
        pm[3]  = (A.u[1] >> 16) | (A.u[2] << 16);
        pm[5]  = (A.u[2] >> 16) | (A.u[3] << 16);
        pm[7]  = (A.u[3] >> 16) | (B.u[0] << 16);
        pm[9]  = (B.u[0] >> 16) | (B.u[1] << 16);
        pm[11] = (B.u[1] >> 16) | (B.u[2] << 16);
        #pragma unroll
        for (int kx = 0; kx < 7; ++kx) {
            HU w; w.u = wp2[ky * 7 + kx];
            #pragma unroll
            for (int p = 0; p < 4; ++p) {
                HU m; m.u = pm[kx + 2 * p];
                acc2[p] = m.h * w.h + acc2[p];    // v_pk_fma_f16
            }
        }
    }
    _Float16* op = f + (size_t)bc * NPIX + (oy0 + ty) * Ww + ox0 + tx * 8;
    h8 o;
    #pragma unroll
    for (int p = 0; p < 4; ++p) {
        o[2 * p] = acc2[p].x;
        o[2 * p + 1] = acc2[p].y;
    }
    *(h8*)op = o;
    float s = 0.f;
    #pragma unroll
    for (int p = 0; p < 4; ++p)
        s += (float)acc2[p].x + (float)acc2[p].y;
    #pragma unroll
    for (int off = 32; off > 0; off >>= 1) s += __shfl_down(s, off, 64);
    if ((tid & 63) == 0) red[tid >> 6] = s;
    __syncthreads();
    if (tid == 0)
        partial[bc * 8 + blockIdx.y * 2 + blockIdx.x] =
            (red[0] + red[1]) + (red[2] + red[3]);
}

// fast erf (A&S 7.1.26, |err|<=1.5e-7)
__device__ __forceinline__ float fast_gelu(float v) {
    float z = fabsf(v) * 0.70710678118654752440f;
    float t = 1.0f / fmaf(0.3275911f, z, 1.0f);
    float poly = t * fmaf(t, fmaf(t, fmaf(t, fmaf(t, 1.061405429f, -1.453152027f),
                          1.421413741f), -0.284496736f), 0.254829592f);
    float e = exp2f(-1.44269504088896340736f * z * z);
    float erfz = 1.0f - poly * e;
    erfz = (v < 0.0f) ? -erfz : erfz;
    return 0.5f * v * (1.0f + erfz);
}

// -------------------- K3: fused SE-attn + GELU + LN + offset proj
// Block = 64 pixels x 4 channel-groups of 24; u[24]/thread; LDS reductions
// in fixed order (deterministic). Proven round 22.
__global__ __launch_bounds__(256) void k_ln_off(const _Float16* __restrict__ f,
        const float* __restrict__ partial, const float* __restrict__ ca_w1,
        const float* __restrict__ ca_w2, const float* __restrict__ ln_g,
        const float* __restrict__ ln_b, const float* __restrict__ off_w,
        float* __restrict__ offs) {
    __shared__ float pm[Cc], hh[CR];
    __shared__ float sa[Cc], sg[Cc], sb[Cc], sw0[Cc], sw1[Cc];
    __shared__ float red1[4][64], red2[4][64];
    const int t = threadIdx.x;
    const int b = blockIdx.x >> 8;               // 4096 blocks: 256 per batch
    const int pixbase = (blockIdx.x & 255) * 64;
    const int po = t & 63;                       // pixel offset 0..63
    const int cg = t >> 6;                       // channel group 0..3
    const int pix = pixbase + po;
    if (t < Cc) {
        float s = 0.f;
        const float* p = partial + (b * Cc + t) * 8;
        #pragma unroll
        for (int i = 0; i < 8; ++i) s += p[i];
        pm[t] = s * (1.0f / (float)NPIX);
        sg[t] = ln_g[t];
        sb[t] = ln_b[t];
        sw0[t] = off_w[t];
        sw1[t] = off_w[Cc + t];
    }
    __syncthreads();
    if (t < CR) {
        float s = 0.f;
        for (int c0 = 0; c0 < Cc; ++c0) s = fmaf(ca_w1[t * Cc + c0], pm[c0], s);
        hh[t] = fmaxf(s, 0.f);
    }
    __syncthreads();
    if (t < Cc) {
        float s = 0.f;
        #pragma unroll
        for (int r = 0; r < CR; ++r) s = fmaf(ca_w2[t * CR + r], hh[r], s);
        sa[t] = 1.0f / (1.0f + expf(-s));
    }
    __syncthreads();
    const _Float16* fp = f + (size_t)b * Cc * NPIX + pix;
    float u[24];
    float s1 = 0.f, s2 = 0.f;
    #pragma unroll
    for (int i = 0; i < 24; ++i) {
        const int c = cg * 24 + i;
        float g = fast_gelu((float)fp[(size_t)c * NPIX] * sa[c]);
        u[i] = g;
        s1 += g;
        s2 = fmaf(g, g, s2);
    }
    red1[cg][po] = s1;
    red2[cg][po] = s2;
    __syncthreads();
    const float S1 = ((red1[0][po] + red1[1][po]) + (red1[2][po] + red1[3][po]));
    const float S2 = ((red2[0][po] + red2[1][po]) + (red2[2][po] + red2[3][po]));
    const float mu = S1 * (1.0f / (float)Cc);
    const float var = fmaxf(S2 * (1.0f / (float)Cc) - mu * mu, 0.f);
    const float rs = rsqrtf(var + 1e-5f);
    __syncthreads();                              // readers done before rewrite
    float o0 = 0.f, o1 = 0.f;
    #pragma unroll
    for (int i = 0; i < 24; ++i) {
        const int c = cg * 24 + i;
        float v = (u[i] - mu) * rs * sg[c] + sb[c];
        o0 = fmaf(sw0[c], v, o0);
        o1 = fmaf(sw1[c], v, o1);
    }
    red1[cg][po] = o0;
    red2[cg][po] = o1;
    __syncthreads();
    if (cg == 0) {
        float O0 = ((red1[0][po] + red1[1][po]) + (red1[2][po] + red1[3][po]));
        float O1 = ((red2[0][po] + red2[1][po]) + (red2[2][po] + red2[3][po]));
        offs[(size_t)b * 2 * NPIX + pix] = O0;
        offs[(size_t)b * 2 * NPIX + NPIX + pix] = O1;
    }
}

// -------------------- K-TRG: fused NCHW->NHWC(f16) transpose + FP64 argmax
__global__ __launch_bounds__(256) void k_trg(const float* __restrict__ x,
        const float* __restrict__ centers, _Float16* __restrict__ xnh,
        int* __restrict__ gid) {
    __shared__ float lds[Cc * 129];
    __shared__ double scn[Mm * Cc];
    __shared__ double pacc[Mm * 129];
    const int bid = blockIdx.x;                // 0..2047
    const int b = bid >> 7;
    const int p0 = (bid & 127) * 128;
    const int t = threadIdx.x;
    const int px = t & 127, crow = t >> 7;
    const float* xp = x + (size_t)b * Cc * NPIX + p0 + px;
    #pragma unroll
    for (int it = 0; it < 48; ++it) {
        const int c = it * 2 + crow;
        lds[c * 129 + px] = xp[(size_t)c * NPIX];
    }
    if (t < Mm) {
        double ss = 0.0;
        #pragma unroll
        for (int c = 0; c < Cc; ++c) {
            double v = (double)centers[t * Cc + c];
            ss += v * v;
        }
        double inv = 1.0 / fmax(sqrt(ss), 1e-12);
        #pragma unroll
        for (int c = 0; c < Cc; ++c)
            scn[t * Cc + c] = (double)centers[t * Cc + c] * inv;
    }
    __syncthreads();
    _Float16* ob = xnh + ((size_t)b * NPIX + p0) * Cc;
    #pragma unroll
    for (int i = 0; i < 6; ++i) {
        const int idx = i * 256 + t;           // 0..1535
        const int gpos = idx * 8;              // f16 index in strip (12288)
        const int ppx = gpos / 96;
        const int c = gpos - ppx * 96;         // multiple of 8
        h8 v;
        #pragma unroll
        for (int k = 0; k < 8; ++k)
            v[k] = (_Float16)lds[(c + k) * 129 + ppx];
        *(h8*)(ob + gpos) = v;
    }
    const int c0 = crow * 48;
    double acc[Mm];
    #pragma unroll
    for (int m = 0; m < Mm; ++m) acc[m] = 0.0;
    for (int cc2 = 0; cc2 < 48; ++cc2) {
        const int c = c0 + cc2;
        double xv = (double)lds[c * 129 + px];
        #pragma unroll
        for (int m = 0; m < Mm; ++m)
            acc[m] = fma(xv, scn[m * Cc + c], acc[m]);
    }
    if (crow == 1) {
        #pragma unroll
        for (int m = 0; m < Mm; ++m) pacc[m * 129 + px] = acc[m];
    }
    __syncthreads();
    if (crow == 0) {
        int bi = 0;
        double bv = acc[0] + pacc[0 * 129 + px];
        #pragma unroll
        for (int m = 1; m < Mm; ++m) {
            double v = acc[m] + pacc[m * 129 + px];
            if (v > bv) { bv = v; bi = m; }
        }
        gid[(size_t)b * NPIX + p0 + px] = bi;
    }
}

// -------------------- K5: stable counting sort; + centers copy (block 0)
__global__ __launch_bounds__(256) void k_sort(const int* __restrict__ gid,
        const float* __restrict__ centers, int* __restrict__ iperm,
        int* __restrict__ permi, float* __restrict__ out) {
    __shared__ int hist[256 * Mm];
    __shared__ int tot[Mm];
    const int t = threadIdx.x;
    const int b = blockIdx.x;
    if (b == 0) {  // centers copy (output 2)
        const size_t base = (size_t)Bc * Cc * NPIX + (size_t)Bc * NPIX;
        for (int i = t; i < Mm * Cc; i += 256) out[base + i] = centers[i];
    }
    for (int i = t; i < 256 * Mm; i += 256) hist[i] = 0;
    __syncthreads();
    const int* gp = gid + (size_t)b * NPIX;
    const int base = t * 64;
    for (int i = 0; i < 64; ++i) hist[t * Mm + gp[base + i]] += 1;
    __syncthreads();
    if (t < Mm) {
        int run = 0;
        for (int r = 0; r < 256; ++r) {
            int v = hist[r * Mm + t];
            hist[r * Mm + t] = run;
            run += v;
        }
        tot[t] = run;
    }
    __syncthreads();
    if (t == 0) {
        int run = 0;
        for (int m = 0; m < Mm; ++m) { int v = tot[m]; tot[m] = run; run += v; }
    }
    __syncthreads();
    int* ip = iperm + (size_t)b * NPIX;
    int* pi = permi + (size_t)b * NPIX;
    float* fperm = out + (size_t)Bc * Cc * NPIX + (size_t)b * NPIX;
    for (int i = 0; i < 64; ++i) {
        int src = base + i;
        int g = gp[src];
        int pos = tot[g] + hist[t * Mm + g];
        hist[t * Mm + g] += 1;
        ip[src] = pos;
        pi[pos] = src;
        fperm[pos] = (float)src;
    }
}

// -------------------- K6-FAST: output-position-ordered f16-NHWC sampler
__global__ __launch_bounds__(256) void k_sample_nhwc(
        const _Float16* __restrict__ xnh, const float* __restrict__ R,
        const float* __restrict__ offs, const int* __restrict__ permi,
        float* __restrict__ out) {
    const int lin = blockIdx.x;                    // 0..4095
    const int swz = (lin & 7) * 512 + (lin >> 3);  // 2 batches per XCD
    const int b = swz >> 8;
    const int jbase = (swz & 255) * 64;
    __shared__ float lds[64 * 97];
    __shared__ float swx[64], swy[64], srb[64];
    __shared__ int sr0[64], sr1[64], shi[64];
    const int t = threadIdx.x;
    if (t < 64) {
        const int src = permi[(size_t)b * NPIX + jbase + t];
        const int hh = src >> 7, wwp = src & 127;
        float o0 = offs[(size_t)b * 2 * NPIX + src];
        float o1 = offs[(size_t)b * 2 * NPIX + NPIX + src];
        float gx = -1.0f + (float)wwp * (2.0f / 127.0f) + o0;
        float gy = -1.0f + (float)hh * (2.0f / 127.0f) + o1;
        float px = fminf(fmaxf((gx + 1.0f) * ((float)Ww * 0.5f) - 0.5f, 0.0f), (float)(Ww - 1));
        float py = fminf(fmaxf((gy + 1.0f) * ((float)Hh * 0.5f) - 0.5f, 0.0f), (float)(Hh - 1));
        float x0f = floorf(px), y0f = floorf(py);
        float wx = px - x0f, wy = py - y0f;
        int x0 = (int)x0f, y0 = (int)y0f;
        int y1 = min(y0 + 1, Hh - 1);
        const bool hi = (x0 == Ww - 1);
        const int xb = hi ? (Ww - 2) : x0;
        const int r0 = y0 * Ww + xb, r1 = y1 * Ww + xb;
        float rb;
        {
            f2 t0 = *(const f2*)(R + r0);
            f2 t1 = *(const f2*)(R + r1);
            float v00 = hi ? t0.y : t0.x, v01 = t0.y;
            float v10 = hi ? t1.y : t1.x, v11 = t1.y;
            float top = v00 * (1.0f - wx) + v01 * wx;
            float bot = v10 * (1.0f - wx) + v11 * wx;
            rb = top * (1.0f - wy) + bot * wy;
        }
        swx[t] = wx; swy[t] = wy; srb[t] = rb;
        sr0[t] = r0; sr1[t] = r1;
        shi[t] = hi ? 1 : 0;
    }
    __syncthreads();
    {
        const int px = t >> 2, part = t & 3;
        const float wx = swx[px], wy = swy[px], rb = srb[px];
        const bool hi = shi[px] != 0;
        const _Float16* base0 = xnh + ((size_t)b * NPIX + sr0[px]) * Cc + part * 24;
        const _Float16* base1 = xnh + ((size_t)b * NPIX + sr1[px]) * Cc + part * 24;
        float* lp = &lds[px * 97 + part * 24];
        #pragma unroll
        for (int i = 0; i < 3; ++i) {          // 3 x 8 channels
            h8 A = *(const h8*)(base0 + i * 8);
            h8 B = *(const h8*)(base0 + Cc + i * 8);
            h8 C = *(const h8*)(base1 + i * 8);
            h8 D = *(const h8*)(base1 + Cc + i * 8);
            #pragma unroll
            for (int k = 0; k < 8; ++k) {
                float a = (float)A[k], bb = (float)B[k];
                float cc = (float)C[k], dd = (float)D[k];
                float v00 = hi ? bb : a,  v01 = bb;
                float v10 = hi ? dd : cc, v11 = dd;
                float top = v00 * (1.0f - wx) + v01 * wx;
                float bot = v10 * (1.0f - wx) + v11 * wx;
                lp[i * 8 + k] = top * (1.0f - wy) + bot * wy + rb;
            }
        }
    }
    __syncthreads();
    {
        const int jo = t & 63, cq = t >> 6;
        float* ob = out + (size_t)b * Cc * NPIX + jbase + jo;
        const float* lp = &lds[jo * 97 + cq * 24];
        #pragma unroll
        for (int i = 0; i < 24; ++i) {
            const int c = cq * 24 + i;
            ob[(size_t)c * NPIX] = lp[i];
        }
    }
}

// -------------------- K6-FALLBACK: NCHW sampler (f32 x)
__global__ __launch_bounds__(256, 4) void k_sample(const float* __restrict__ x,
        const float* __restrict__ R, const float* __restrict__ offs,
        const int* __restrict__ iperm, float* __restrict__ out) {
    const int lin = blockIdx.x;
    const int swz = (lin & 7) * 128 + (lin >> 3);
    const int tid = threadIdx.x;
    const int b = swz >> 6;
    const int pix = ((swz & 63) << 8) + tid;
    const int hh = pix >> 7, wwp = pix & 127;
    float o0 = offs[(size_t)b * 2 * NPIX + pix];
    float o1 = offs[(size_t)b * 2 * NPIX + NPIX + pix];
    float gx = -1.0f + (float)wwp * (2.0f / 127.0f) + o0;
    float gy = -1.0f + (float)hh * (2.0f / 127.0f) + o1;
    float px = fminf(fmaxf((gx + 1.0f) * ((float)Ww * 0.5f) - 0.5f, 0.0f), (float)(Ww - 1));
    float py = fminf(fmaxf((gy + 1.0f) * ((float)Hh * 0.5f) - 0.5f, 0.0f), (float)(Hh - 1));
    float x0f = floorf(px), y0f = floorf(py);
    float wx = px - x0f, wy = py - y0f;
    int x0 = (int)x0f, y0 = (int)y0f;
    int y1 = min(y0 + 1, Hh - 1);
    const bool hi = (x0 == Ww - 1);
    const int xb = hi ? (Ww - 2) : x0;
    const int r0 = y0 * Ww + xb, r1 = y1 * Ww + xb;
    float rb;
    {
        f2 t0 = *(const f2*)(R + r0);
        f2 t1 = *(const f2*)(R + r1);
        float v00 = hi ? t0.y : t0.x, v01 = t0.y;
        float v10 = hi ? t1.y : t1.x, v11 = t1.y;
        float top = v00 * (1.0f - wx) + v01 * wx;
        float bot = v10 * (1.0f - wx) + v11 * wx;
        rb = top * (1.0f - wy) + bot * wy;
    }
    const int c0 = blockIdx.y * CPG;
    const int j = iperm[(size_t)b * NPIX + pix];
    const float* xp = x + (size_t)b * Cc * NPIX + (size_t)c0 * NPIX;
    float* op = out + (size_t)b * Cc * NPIX + (size_t)c0 * NPIX + j;
    f2 t0[CPG], t1[CPG];
    #pragma unroll
    for (int c = 0; c < CPG; ++c) {
        const float* xc = xp + (size_t)c * NPIX;
        t0[c] = *(const f2*)(xc + r0);
        t1[c] = *(const f2*)(xc + r1);
    }
    #pragma unroll
    for (int c = 0; c < CPG; ++c) {
        float v00 = hi ? t0[c].y : t0[c].x, v01 = t0[c].y;
        float v10 = hi ? t1[c].y : t1[c].x, v11 = t1[c].y;
        float top = v00 * (1.0f - wx) + v01 * wx;
        float bot = v10 * (1.0f - wx) + v11 * wx;
        op[(size_t)c * NPIX] = top * (1.0f - wy) + bot * wy + rb;
    }
}

// fallback-path group kernel (used only when ws too small for xnh)
__global__ __launch_bounds__(256) void k_group(const float* __restrict__ x,
        const float* __restrict__ centers, int* __restrict__ gid) {
    __shared__ double scn[Mm * Cc];
    const int tid = threadIdx.x;
    for (int i = tid; i < Mm * Cc; i += 256) scn[i] = (double)centers[i];
    __syncthreads();
    if (tid < Mm) {
        double ss = 0.0;
        #pragma unroll
        for (int c = 0; c < Cc; ++c) { double v = scn[tid * Cc + c]; ss += v * v; }
        double inv = 1.0 / fmax(sqrt(ss), 1e-12);
        #pragma unroll
        for (int c = 0; c < Cc; ++c) scn[tid * Cc + c] *= inv;
    }
    __syncthreads();
    const int b = blockIdx.x >> 6;
    const int n = ((blockIdx.x & 63) << 8) + tid;
    const float* xp = x + (size_t)b * Cc * NPIX + n;
    double acc[Mm];
    #pragma unroll
    for (int m = 0; m < Mm; ++m) acc[m] = 0.0;
    for (int c = 0; c < Cc; ++c) {
        double xv = (double)xp[(size_t)c * NPIX];
        #pragma unroll
        for (int m = 0; m < Mm; ++m) acc[m] = fma(xv, scn[m * Cc + c], acc[m]);
    }
    int bi = 0;
    double bv = acc[0];
    #pragma unroll
    for (int m = 1; m < Mm; ++m) {
        if (acc[m] > bv) { bv = acc[m]; bi = m; }
    }
    gid[(size_t)b * NPIX + n] = bi;
}

// fallback attn (only for ws-too-small path)
__global__ void k_attn(const float* __restrict__ partial,
        const float* __restrict__ ca_w1, const float* __restrict__ ca_w2,
        float* __restrict__ attnout) {
    __shared__ float pm[Cc];
    __shared__ float hh[CR];
    const int tid = threadIdx.x;
    const int b = blockIdx.x;
    if (tid < Cc) {
        float s = 0.f;
        const float* p = partial + (b * Cc + tid) * 8;
        #pragma unroll
        for (int i = 0; i < 8; ++i) s += p[i];
        pm[tid] = s * (1.0f / (float)NPIX);
    }
    __syncthreads();
    if (tid < CR) {
        float s = 0.f;
        for (int c0 = 0; c0 < Cc; ++c0) s = fmaf(ca_w1[tid * Cc + c0], pm[c0], s);
        hh[tid] = fmaxf(s, 0.f);
    }
    __syncthreads();
    if (tid < Cc) {
        float s = 0.f;
        #pragma unroll
        for (int r = 0; r < CR; ++r) s = fmaf(ca_w2[tid * CR + r], hh[r], s);
        attnout[b * Cc + tid] = 1.0f / (1.0f + expf(-s));
    }
}

extern "C" void kernel_launch(void* const* d_in, const int* in_sizes, int n_in,
                              void* d_out, int out_size, void* d_ws, size_t ws_size,
                              hipStream_t stream) {
    const float* x       = (const float*)d_in[0];
    const float* dw_w    = (const float*)d_in[1];
    const float* dw_b    = (const float*)d_in[2];
    const float* ca_w1   = (const float*)d_in[3];
    const float* ca_w2   = (const float*)d_in[4];
    const float* ln_g    = (const float*)d_in[5];
    const float* ln_b    = (const float*)d_in[6];
    const float* off_w   = (const float*)d_in[7];
    const float* R       = (const float*)d_in[8];
    const float* centers = (const float*)d_in[9];
    float* out = (float*)d_out;

    // workspace: small region (~5.3MB) + optional f16 xnh (50.3MB)
    float* partial = (float*)d_ws;                 // Bc*Cc*8
    float* attn    = partial + Bc * Cc * 8;        // Bc*Cc (fallback path only)
    float* offs    = attn + Bc * Cc;               // Bc*2*NPIX
    int*   gid     = (int*)(offs + Bc * 2 * NPIX); // Bc*NPIX
    int*   iperm   = gid + Bc * NPIX;              // Bc*NPIX
    int*   permi   = iperm + Bc * NPIX;            // Bc*NPIX
    _Float16* xnh  = (_Float16*)(permi + Bc * NPIX); // Bc*NPIX*Cc f16 (optional)

    const size_t small_elems = (size_t)Bc * Cc * 8 + Bc * Cc +
                               (size_t)Bc * 2 * NPIX + 3 * (size_t)Bc * NPIX;
    const size_t need = small_elems * 4 + (size_t)Bc * NPIX * Cc * 2;
    const int do_nhwc = (ws_size >= need) ? 1 : 0;

    // conv output f lives (as f16) in out's map region; dead after ln_off,
    // then overwritten by the sampler's f32 writes.
    _Float16* f = (_Float16*)out;

    hipLaunchKernelGGL(k_conv, dim3(Ww / CTW, Hh / CTH, Bc * Cc), dim3(256), 0,
                       stream, x, dw_w, dw_b, f, partial);
    if (do_nhwc) {
        hipLaunchKernelGGL(k_ln_off, dim3(4096), dim3(256), 0, stream,
                           f, partial, ca_w1, ca_w2, ln_g, ln_b, off_w, offs);
        hipLaunchKernelGGL(k_trg, dim3(2048), dim3(256), 0, stream,
                           x, centers, xnh, gid);
        hipLaunchKernelGGL(k_sort, dim3(Bc), dim3(256), 0, stream,
                           gid, centers, iperm, permi, out);
        hipLaunchKernelGGL(k_sample_nhwc, dim3(4096), dim3(256), 0, stream,
                           xnh, R, offs, permi, out);
    } else {
        hipLaunchKernelGGL(k_ln_off, dim3(4096), dim3(256), 0, stream,
                           f, partial, ca_w1, ca_w2, ln_g, ln_b, off_w, offs);
        hipLaunchKernelGGL(k_group, dim3(1024), dim3(256), 0, stream,
                           x, centers, gid);
        hipLaunchKernelGGL(k_sort, dim3(Bc), dim3(256), 0, stream,
                           gid, centers, iperm, permi, out);
        hipLaunchKernelGGL(k_sample, dim3(1024, CGROUPS), dim3(256), 0, stream,
                           x, R, offs, iperm, out);
    }
}